// Round 17
// baseline (120.987 us; speedup 1.0000x reference)
//
#include <hip/hip_runtime.h>
#include <hip/hip_bf16.h>

#define NNODES 131072
#define NEDGES 2097152
#define BSUB   1024
#define SSUB   128
#define FIN    300
#define FOUT   64
#define NCHUNK 1024
#define CHEDGE 2048

typedef __attribute__((ext_vector_type(8))) short short8;
typedef __attribute__((ext_vector_type(8))) unsigned short ushort8;
typedef __attribute__((ext_vector_type(4))) float f32x4;

// hardware RNE f32->bf16 (compiler lowers pairs to v_cvt_pk_bf16_f32)
__device__ inline unsigned short f2bfbits(float f) {
    union { __hip_bfloat16 h; unsigned short u; } cv;
    cv.h = __float2bfloat16(f);
    return cv.u;
}
__device__ inline float bf2f(unsigned short b) {
    return __uint_as_float(((unsigned)b) << 16);
}

// async global->LDS DMA, 16B per lane; LDS dest = wave-uniform base + lane*16.
__device__ inline void gload_lds16(const float* g, void* l) {
    __builtin_amdgcn_global_load_lds(
        (const __attribute__((address_space(1))) unsigned int*)g,
        (__attribute__((address_space(3))) unsigned int*)l,
        16, 0, 0);
}

// ---------------------------------------------------------------------------
// R17: dispatch-count reduction (4 -> 2). R15/R16 in-kernel rewrites were
// both null -> the pole is per-dispatch overhead, not kernel work.
// front_kernel: blocks [0,1024) = per-chunk counting-sort bucket (R16);
// blocks [1024,3072) = MFMA gemm (R16) with B-fragments loaded DIRECTLY
// from W (predicated scalar loads, W is 75 KB L2-resident) -> no prep
// dispatch, no wfrag dependency, numerically identical.
// ---------------------------------------------------------------------------
__global__ __launch_bounds__(256, 2) void front_kernel(const int* __restrict__ src,
                                                       const int* __restrict__ dst,
                                                       unsigned* __restrict__ ofs,
                                                       unsigned short* __restrict__ bkt,
                                                       const float* __restrict__ x,
                                                       const float* __restrict__ W,
                                                       unsigned short* __restrict__ hb) {
    __shared__ __align__(16) char smem[77824];

    if (blockIdx.x < NCHUNK) {
        // ---------------- bucket path (R16 counting-sort) ----------------
        unsigned short* epack  = (unsigned short*)smem;            // 4 KB
        unsigned short* eg     = (unsigned short*)(smem + 4096);   // 4 KB
        unsigned short* sorted = (unsigned short*)(smem + 8192);   // 4 KB
        int* hist = (int*)(smem + 12288);                          // 4 KB
        int* cur  = (int*)(smem + 16384);                          // 4 KB
        int* wsum = (int*)(smem + 20480);                          // 16 B

        const int cb = blockIdx.x;
        const int t = threadIdx.x;
        for (int i = t; i < BSUB; i += 256) hist[i] = 0;
        __syncthreads();

        const int4* sp = (const int4*)(src + (size_t)cb * CHEDGE);
        const int4* dp = (const int4*)(dst + (size_t)cb * CHEDGE);
        for (int i = t; i < CHEDGE / 4; i += 256) {
            int4 s4 = sp[i], d4 = dp[i];
#pragma unroll
            for (int k = 0; k < 4; ++k) {
                int s = (k == 0) ? s4.x : (k == 1) ? s4.y : (k == 2) ? s4.z : s4.w;
                int d = (k == 0) ? d4.x : (k == 1) ? d4.y : (k == 2) ? d4.z : d4.w;
                int g = s >> 7;
                epack[i * 4 + k] = (unsigned short)(((s & 127) << 7) | (d & 127));
                eg[i * 4 + k] = (unsigned short)g;
                atomicAdd(&hist[g], 1);
            }
        }
        __syncthreads();

        {   // block exclusive scan over 1024 bins (thread t owns bins 4t..4t+3)
            int lane = t & 63, w = t >> 6;
            int c0 = hist[4 * t], c1 = hist[4 * t + 1], c2 = hist[4 * t + 2], c3 = hist[4 * t + 3];
            int s = c0 + c1 + c2 + c3;
            int pre = s;
#pragma unroll
            for (int o = 1; o < 64; o <<= 1) {
                int v = __shfl_up(pre, o, 64);
                if (lane >= o) pre += v;
            }
            if (lane == 63) wsum[w] = pre;
            __syncthreads();
            int wbase = 0;
            for (int i = 0; i < w; ++i) wbase += wsum[i];
            int excl = wbase + pre - s;
            uint4 ov;
            ov.x = ((unsigned)excl << 16) | (unsigned)c0; cur[4 * t]     = excl; excl += c0;
            ov.y = ((unsigned)excl << 16) | (unsigned)c1; cur[4 * t + 1] = excl; excl += c1;
            ov.z = ((unsigned)excl << 16) | (unsigned)c2; cur[4 * t + 2] = excl; excl += c2;
            ov.w = ((unsigned)excl << 16) | (unsigned)c3; cur[4 * t + 3] = excl;
            ((uint4*)(ofs + (size_t)cb * BSUB))[t] = ov;       // coalesced
        }
        __syncthreads();

        for (int i = t; i < CHEDGE; i += 256) {                // LDS scatter
            int g = eg[i];
            int r = atomicAdd(&cur[g], 1);
            sorted[r] = epack[i];
        }
        __syncthreads();

        {   // coalesced streaming writeout (4 KB contiguous)
            ushort8* outv = (ushort8*)(bkt + (size_t)cb * CHEDGE);
            const ushort8* sv = (const ushort8*)sorted;
            for (int i = t; i < CHEDGE / 8; i += 256) outv[i] = sv[i];
        }
        return;
    }

    // ---------------- GEMM path (R16 structure) ----------------
    char* bufA = smem;                  // k[0,128)   rows of 512 B (swizzled)
    char* bufB = smem + 32768;          // k[128,256) rows of 512 B (swizzled)
    char* aux  = smem + 65536;          // tail k[256,300) rows of 176 B; then st

    const int wave = threadIdx.x >> 6;          // = ct (col tile)
    const int lane = threadIdx.x & 63;
    const int rowbase = (blockIdx.x - NCHUNK) * 64;

    // --- A staging DMA first (starts HBM traffic ASAP) ---
#pragma unroll
    for (int i = wave; i < 32; i += 4) {
        int o = i * 1024 + lane * 16;
        int row = o >> 9;
        int c = o & 511;
        int csrc = c ^ ((row & 7) << 4);
        gload_lds16(x + (size_t)(rowbase + row) * FIN + (csrc >> 2), bufA + i * 1024);
    }
#pragma unroll
    for (int i = wave; i < 32; i += 4) {
        int o = i * 1024 + lane * 16;
        int row = o >> 9;
        int c = o & 511;
        int csrc = c ^ ((row & 7) << 4);
        gload_lds16(x + (size_t)(rowbase + row) * FIN + 128 + (csrc >> 2), bufB + i * 1024);
    }
    for (int i = wave; i < 11; i += 4) {        // tail k[256,300): 176 B/row
        int o = i * 1024 + lane * 16;
        int row = o / 176;
        int c = o - row * 176;
        gload_lds16(x + (size_t)(rowbase + row) * FIN + 256 + (c >> 2), aux + i * 1024);
    }
    // zero the aux slack [11264, 12288): kt=9 over-read lands here.
    ((float*)(aux + 11264))[threadIdx.x] = 0.f;

    // --- B fragments DIRECT from W (L2-hot 75 KB; 4 cache lines/instr) ---
    short8 bq[10];
    {
        const int col = wave * 16 + (lane & 15);
        const int krow = (lane >> 4) * 8;
#pragma unroll
        for (int kt = 0; kt < 10; ++kt) {
#pragma unroll
            for (int e = 0; e < 8; ++e) {
                int k = kt * 32 + krow + e;
                float v = (k < FIN) ? W[(size_t)k * FOUT + col] : 0.f;
                bq[kt][e] = (short)f2bfbits(v);
            }
        }
    }

    f32x4 acc[4];
#pragma unroll
    for (int r = 0; r < 4; ++r) acc[r] = (f32x4){0.f, 0.f, 0.f, 0.f};

    const int kg = lane >> 4;

    __syncthreads();    // drains ALL DMA; publishes bufA/bufB/aux

    // --- MFMA loop: rt x kt, pure LDS + registers ---
#pragma unroll
    for (int rt = 0; rt < 4; ++rt) {
        const int rl = rt * 16 + (lane & 15);
        const int sw = (rl & 7) << 4;
#pragma unroll
        for (int kt = 0; kt < 10; ++kt) {
            f32x4 lo, hi;
            if (kt < 8) {
                const char* buf = (kt < 4) ? bufA : bufB;
                int c0 = (kt & 3) * 128 + kg * 32;
                lo = *(const f32x4*)(buf + rl * 512 + (c0 ^ sw));
                hi = *(const f32x4*)(buf + rl * 512 + ((c0 + 16) ^ sw));
            } else {
                int c0 = (kt - 8) * 128 + kg * 32;
                lo = *(const f32x4*)(aux + rl * 176 + c0);
                hi = *(const f32x4*)(aux + rl * 176 + c0 + 16);
            }
            short8 afr;
            afr[0] = (short)f2bfbits(lo[0]); afr[1] = (short)f2bfbits(lo[1]);
            afr[2] = (short)f2bfbits(lo[2]); afr[3] = (short)f2bfbits(lo[3]);
            afr[4] = (short)f2bfbits(hi[0]); afr[5] = (short)f2bfbits(hi[1]);
            afr[6] = (short)f2bfbits(hi[2]); afr[7] = (short)f2bfbits(hi[3]);
            acc[rt] = __builtin_amdgcn_mfma_f32_16x16x32_bf16(afr, bq[kt], acc[rt], 0, 0, 0);
        }
    }

    __syncthreads();    // all waves done reading aux (tail) -> safe to reuse

    // --- epilogue: block transpose in aux -> coalesced 16B stores ---
    {
        unsigned short* st = (unsigned short*)aux;      // [64][64] u16 = 8 KB
        const int colb = wave * 16 + (lane & 15);
#pragma unroll
        for (int rt = 0; rt < 4; ++rt) {
            const int rbase = rt * 16 + (lane >> 4) * 4;
#pragma unroll
            for (int r = 0; r < 4; ++r)
                st[(rbase + r) * FOUT + colb] = f2bfbits(acc[rt][r]);
        }
        __syncthreads();
        const ushort8* sv = (const ushort8*)st;                 // 512 x 16B
        ushort8* hout = (ushort8*)(hb + (size_t)rowbase * FOUT);
        hout[threadIdx.x] = sv[threadIdx.x];
        hout[threadIdx.x + 256] = sv[threadIdx.x + 256];
    }
}

// ---------------------------------------------------------------------------
// Per-subgraph aggregate + norm + PReLU + pool + anchor (R16, unchanged).
// ---------------------------------------------------------------------------
__global__ __launch_bounds__(256) void agg_pool_kernel(const unsigned short* __restrict__ hb,
                                                       const unsigned short* __restrict__ bkt,
                                                       const unsigned* __restrict__ ofs,
                                                       const float* __restrict__ bias,
                                                       const float* __restrict__ prelu,
                                                       float* __restrict__ out) {
    __shared__ unsigned short hl[SSUB][FOUT];       // 16 KB bf16 bits
    __shared__ unsigned short el[4096];             // 8 KB contiguous edge list
    __shared__ unsigned char  es[SSUB][64];         // 8 KB per-dst src lists
    __shared__ int   din[SSUB];
    __shared__ int   dout[SSUB];
    __shared__ float rout[SSUB];
    __shared__ float ps[4][FOUT];
    __shared__ int   wsum[4];

    const int g = blockIdx.x;
    const int t = threadIdx.x;
    const int lane = t & 63;
    const int w = t >> 6;

    // Phase 1: 4 run descriptors + block exclusive scan of their total
    unsigned w32[4];
    int rst[4], cn[4];
    int mycnt = 0;
#pragma unroll
    for (int j = 0; j < 4; ++j) {
        w32[j] = ofs[(size_t)(4 * t + j) * BSUB + g];
        rst[j] = (int)(w32[j] >> 16);
        cn[j] = (int)(w32[j] & 0xffff);
        mycnt += cn[j];
    }
    int pre = mycnt;
#pragma unroll
    for (int o = 1; o < 64; o <<= 1) {
        int v = __shfl_up(pre, o, 64);
        if (lane >= o) pre += v;
    }
    if (lane == 63) wsum[w] = pre;

    // overlap: load h tile (coalesced) while scan propagates
    {
        const ushort8* hsrc = (const ushort8*)(hb + (size_t)g * SSUB * FOUT);
        ushort8* hdst = (ushort8*)&hl[0][0];
        for (int i = t; i < 1024; i += 256) hdst[i] = hsrc[i];
    }
    if (t < SSUB) { din[t] = 0; dout[t] = 0; }
    __syncthreads();

    int wbase = 0;
    for (int i = 0; i < w; ++i) wbase += wsum[i];
    int myoff = wbase + pre - mycnt;                    // exclusive prefix
    const int cnt = wsum[0] + wsum[1] + wsum[2] + wsum[3];

    // Phase 2: cooperative copy of 4 runs -> contiguous LDS
    {
        int o = myoff;
#pragma unroll
        for (int j = 0; j < 4; ++j) {
            const unsigned short* ebb = bkt + ((size_t)(4 * t + j) << 11) + rst[j];
            int lim = min(cn[j], 4096 - o);             // defensive clamp
            for (int i = 0; i < lim; ++i) el[o + i] = ebb[i];
            o += lim;
        }
    }
    __syncthreads();

    // Phase 3: degree count + per-dst list build, LDS-sourced, coalesced
    for (int i = t; i < cnt; i += 256) {
        unsigned e = el[i];
        int s = e >> 7, d = e & 127;
        int r = atomicAdd(&din[d], 1);
        es[d][r & 63] = (unsigned char)s;
        atomicAdd(&dout[s], 1);
    }
    __syncthreads();
    if (t < SSUB) rout[t] = rsqrtf((float)max(dout[t], 1));
    __syncthreads();

    // register aggregation: wave w owns dst rows w, w+4, ...
    const float bv = bias[lane];
    const float a = prelu[0];
    float pool = 0.f;
#pragma unroll 4
    for (int ii = 0; ii < 32; ++ii) {
        int d = w + 4 * ii;
        int cd = min(din[d], 64);
        float accv = 0.f;
        const unsigned* ew = (const unsigned*)&es[d][0];
        int nw = (cd + 3) >> 2;
        for (int p = 0; p < nw; ++p) {
            unsigned wd = ew[p];                        // broadcast LDS read
            int rem = cd - p * 4;
#pragma unroll
            for (int b = 0; b < 4; ++b) {
                if (b < rem) {                          // wave-uniform predicate
                    int s = (wd >> (8 * b)) & 127;
                    accv += bf2f(hl[s][lane]) * rout[s];
                }
            }
        }
        float v = accv * rsqrtf((float)max(din[d], 1)) + bv;
        v = (v > 0.f) ? v : a * v;
        if (d == SSUB - 1)
            out[(size_t)(BSUB + g) * FOUT + lane] = v;  // anchor (wave 3)
        else
            pool += v;
    }
    ps[w][lane] = pool;
    __syncthreads();
    if (w == 0) {
        float s = (ps[0][lane] + ps[1][lane]) + (ps[2][lane] + ps[3][lane]);
        out[(size_t)g * FOUT + lane] = s * (1.0f / 127.0f);
    }
}

// ---------------------------------------------------------------------------
extern "C" void kernel_launch(void* const* d_in, const int* in_sizes, int n_in,
                              void* d_out, int out_size, void* d_ws, size_t ws_size,
                              hipStream_t stream) {
    const float* in_feat = (const float*)d_in[0];
    const float* W       = (const float*)d_in[1];
    const float* bias    = (const float*)d_in[2];
    const float* prelu   = (const float*)d_in[3];
    const int*   src     = (const int*)d_in[4];
    const int*   dst     = (const int*)d_in[5];
    float* out = (float*)d_out;

    char* ws = (char*)d_ws;
    unsigned*       ofs = (unsigned*)(ws + (2u << 20));        // 4 MB (1024x1024 u32)
    unsigned short* bkt = (unsigned short*)(ws + (8u << 20));  // 4 MB (1024x2048 u16)
    unsigned short* hb  = (unsigned short*)(ws + (16u << 20)); // 16 MB bf16 h

    hipLaunchKernelGGL(front_kernel,    dim3(NCHUNK + NNODES/64), dim3(256), 0, stream,
                       src, dst, ofs, bkt, in_feat, W, hb);
    hipLaunchKernelGGL(agg_pool_kernel, dim3(BSUB),               dim3(256), 0, stream,
                       hb, bkt, ofs, bias, prelu, out);
}

// Round 20
// 103.131 us; speedup vs baseline: 1.1731x; 1.1731x over previous
//
#include <hip/hip_runtime.h>
#include <hip/hip_bf16.h>

#define NNODES 131072
#define NEDGES 2097152
#define BSUB   1024
#define SSUB   128
#define FIN    300
#define FOUT   64
#define NCHUNK 256
#define CHEDGE 8192

typedef __attribute__((ext_vector_type(8))) short short8;
typedef __attribute__((ext_vector_type(8))) unsigned short ushort8;
typedef __attribute__((ext_vector_type(4))) float f32x4;

// hardware RNE f32->bf16 (compiler lowers pairs to v_cvt_pk_bf16_f32)
__device__ inline unsigned short f2bfbits(float f) {
    union { __hip_bfloat16 h; unsigned short u; } cv;
    cv.h = __float2bfloat16(f);
    return cv.u;
}
__device__ inline float bf2f(unsigned short b) {
    return __uint_as_float(((unsigned)b) << 16);
}
__device__ inline void gload_lds16(const float* g, void* l) {
    __builtin_amdgcn_global_load_lds(
        (const __attribute__((address_space(1))) unsigned int*)g,
        (__attribute__((address_space(3))) unsigned int*)l,
        16, 0, 0);
}

// ---------------------------------------------------------------------------
// R20: the proven R13 pipeline (best measured: 108.0 us), 4 -> 3 dispatches.
// bucket_kernel grid = NCHUNK+10: blocks [0,256) do the per-chunk counting
// sort (R13 body, unchanged); blocks [256,266) do prep_w (pack W into MFMA
// B-fragment layout). Tiny prep blocks can't perturb bucket occupancy.
// Cooperative/grid-sync approaches are ABANDONED: including the cg header
// broke device-code load for the whole .so in R18/R19 (all kernels no-op'd).
// ---------------------------------------------------------------------------
__global__ __launch_bounds__(256) void bucket_prep_kernel(const int* __restrict__ src,
                                                          const int* __restrict__ dst,
                                                          unsigned* __restrict__ ofs,
                                                          unsigned short* __restrict__ bkt,
                                                          const float* __restrict__ W,
                                                          short* __restrict__ wfrag) {
    __shared__ unsigned short epack[CHEDGE];    // 16 KB
    __shared__ unsigned short eg[CHEDGE];       // 16 KB
    __shared__ unsigned short sorted[CHEDGE];   // 16 KB
    __shared__ int hist[BSUB];                  // 4 KB
    __shared__ int cur[BSUB];                   // 4 KB
    __shared__ int wsum[4];

    if (blockIdx.x >= NCHUNK) {
        // ---- prep_w role (blocks 256..265; 2560 fragment-units total) ----
        int idx = (blockIdx.x - NCHUNK) * 256 + threadIdx.x;
        if (idx < 2560) {
            int ct   = idx / 640;
            int rem  = idx % 640;
            int kt   = rem / 64;
            int lane = rem % 64;
            int col  = ct * 16 + (lane & 15);
            int kb   = kt * 32 + (lane >> 4) * 8;
#pragma unroll
            for (int e = 0; e < 8; ++e) {
                int k = kb + e;
                float v = (k < FIN) ? W[(size_t)k * FOUT + col] : 0.f;
                wfrag[(size_t)idx * 8 + e] = (short)f2bfbits(v);
            }
        }
        return;
    }

    // ---- bucket role (R13 counting-sort, unchanged) ----
    const int cb = blockIdx.x;
    const int t = threadIdx.x;
    for (int i = t; i < BSUB; i += 256) hist[i] = 0;
    __syncthreads();

    const int4* sp = (const int4*)(src + (size_t)cb * CHEDGE);
    const int4* dp = (const int4*)(dst + (size_t)cb * CHEDGE);
    for (int i = t; i < CHEDGE / 4; i += 256) {
        int4 s4 = sp[i], d4 = dp[i];
#pragma unroll
        for (int k = 0; k < 4; ++k) {
            int s = (k == 0) ? s4.x : (k == 1) ? s4.y : (k == 2) ? s4.z : s4.w;
            int d = (k == 0) ? d4.x : (k == 1) ? d4.y : (k == 2) ? d4.z : d4.w;
            int g = s >> 7;
            epack[i * 4 + k] = (unsigned short)(((s & 127) << 7) | (d & 127));
            eg[i * 4 + k] = (unsigned short)g;
            atomicAdd(&hist[g], 1);
        }
    }
    __syncthreads();

    {   // block exclusive scan over 1024 bins (thread t owns bins 4t..4t+3)
        int lane = t & 63, w = t >> 6;
        int c0 = hist[4 * t], c1 = hist[4 * t + 1], c2 = hist[4 * t + 2], c3 = hist[4 * t + 3];
        int s = c0 + c1 + c2 + c3;
        int pre = s;
#pragma unroll
        for (int o = 1; o < 64; o <<= 1) {
            int v = __shfl_up(pre, o, 64);
            if (lane >= o) pre += v;
        }
        if (lane == 63) wsum[w] = pre;
        __syncthreads();
        int wbase = 0;
        for (int i = 0; i < w; ++i) wbase += wsum[i];
        int excl = wbase + pre - s;
        uint4 ov;
        ov.x = ((unsigned)excl << 16) | (unsigned)c0; cur[4 * t]     = excl; excl += c0;
        ov.y = ((unsigned)excl << 16) | (unsigned)c1; cur[4 * t + 1] = excl; excl += c1;
        ov.z = ((unsigned)excl << 16) | (unsigned)c2; cur[4 * t + 2] = excl; excl += c2;
        ov.w = ((unsigned)excl << 16) | (unsigned)c3; cur[4 * t + 3] = excl;
        ((uint4*)(ofs + (size_t)cb * BSUB))[t] = ov;       // coalesced 16B/thread
    }
    __syncthreads();

    // LDS scatter (int atomics on cur, LDS-speed)
    for (int i = t; i < CHEDGE; i += 256) {
        int g = eg[i];
        int r = atomicAdd(&cur[g], 1);
        sorted[r] = epack[i];
    }
    __syncthreads();

    // coalesced streaming writeout (16 KB contiguous)
    {
        ushort8* outv = (ushort8*)(bkt + (size_t)cb * CHEDGE);
        const ushort8* sv = (const ushort8*)sorted;
        for (int i = t; i < CHEDGE / 8; i += 256) outv[i] = sv[i];
    }
}

// ---------------------------------------------------------------------------
// h = in_feat @ W, bf16 MFMA 16x16x32 (R12/R13 structure, ~23 us == HBM
// floor for the 157 MB read, established by the R12 duplicate-launch delta).
// ---------------------------------------------------------------------------
__global__ __launch_bounds__(256, 2) void gemm_kernel(const float* __restrict__ x,
                                                      const short* __restrict__ wfrag,
                                                      unsigned short* __restrict__ hb) {
    __shared__ __align__(16) char smem[77824];      // 32K bufA + 32K bufB + 12K aux
    char* bufA = smem;                  // k[0,128)   rows of 512 B (swizzled)
    char* bufB = smem + 32768;          // k[128,256) rows of 512 B (swizzled)
    char* aux  = smem + 65536;          // tail k[256,300) rows of 176 B; then st

    const int wave = threadIdx.x >> 6;          // = ct (col tile)
    const int lane = threadIdx.x & 63;
    const int rowbase = blockIdx.x * 64;

    // B preload: this wave's 10 fragments -> 40 VGPRs (coalesced 16B)
    short8 bq[10];
#pragma unroll
    for (int kt = 0; kt < 10; ++kt)
        bq[kt] = *(const short8*)(wfrag + ((size_t)(wave * 10 + kt) * 64 + lane) * 8);

    // A staging DMA: contiguous, source pre-swizzled
#pragma unroll
    for (int i = wave; i < 32; i += 4) {
        int o = i * 1024 + lane * 16;
        int row = o >> 9;
        int c = o & 511;
        int csrc = c ^ ((row & 7) << 4);
        gload_lds16(x + (size_t)(rowbase + row) * FIN + (csrc >> 2), bufA + i * 1024);
    }
#pragma unroll
    for (int i = wave; i < 32; i += 4) {
        int o = i * 1024 + lane * 16;
        int row = o >> 9;
        int c = o & 511;
        int csrc = c ^ ((row & 7) << 4);
        gload_lds16(x + (size_t)(rowbase + row) * FIN + 128 + (csrc >> 2), bufB + i * 1024);
    }
    // tail k[256,300): 176 B/row, 64 rows = 11264 B into aux (11 insts)
    for (int i = wave; i < 11; i += 4) {
        int o = i * 1024 + lane * 16;
        int row = o / 176;
        int c = o - row * 176;
        gload_lds16(x + (size_t)(rowbase + row) * FIN + 256 + (c >> 2), aux + i * 1024);
    }
    // zero the aux slack [11264, 12288): kt=9 over-read lands here.
    ((float*)(aux + 11264))[threadIdx.x] = 0.f;

    f32x4 acc[4];
#pragma unroll
    for (int r = 0; r < 4; ++r) acc[r] = (f32x4){0.f, 0.f, 0.f, 0.f};

    const int kg = lane >> 4;

    __syncthreads();    // drains ALL DMA; publishes bufA/bufB/aux

    // MFMA loop: rt x kt, pure LDS + registers
#pragma unroll
    for (int rt = 0; rt < 4; ++rt) {
        const int rl = rt * 16 + (lane & 15);
        const int sw = (rl & 7) << 4;
#pragma unroll
        for (int kt = 0; kt < 10; ++kt) {
            f32x4 lo, hi;
            if (kt < 8) {
                const char* buf = (kt < 4) ? bufA : bufB;
                int c0 = (kt & 3) * 128 + kg * 32;
                lo = *(const f32x4*)(buf + rl * 512 + (c0 ^ sw));
                hi = *(const f32x4*)(buf + rl * 512 + ((c0 + 16) ^ sw));
            } else {
                int c0 = (kt - 8) * 128 + kg * 32;
                lo = *(const f32x4*)(aux + rl * 176 + c0);
                hi = *(const f32x4*)(aux + rl * 176 + c0 + 16);
            }
            short8 afr;
            afr[0] = (short)f2bfbits(lo[0]); afr[1] = (short)f2bfbits(lo[1]);
            afr[2] = (short)f2bfbits(lo[2]); afr[3] = (short)f2bfbits(lo[3]);
            afr[4] = (short)f2bfbits(hi[0]); afr[5] = (short)f2bfbits(hi[1]);
            afr[6] = (short)f2bfbits(hi[2]); afr[7] = (short)f2bfbits(hi[3]);
            acc[rt] = __builtin_amdgcn_mfma_f32_16x16x32_bf16(afr, bq[kt], acc[rt], 0, 0, 0);
        }
    }

    __syncthreads();    // all waves done reading aux tail -> safe to reuse

    // epilogue: block transpose in aux -> coalesced 16B stores
    {
        unsigned short* st = (unsigned short*)aux;      // [64][64] u16 = 8 KB
        const int colb = wave * 16 + (lane & 15);
#pragma unroll
        for (int rt = 0; rt < 4; ++rt) {
            const int rbase = rt * 16 + (lane >> 4) * 4;
#pragma unroll
            for (int r = 0; r < 4; ++r)
                st[(rbase + r) * FOUT + colb] = f2bfbits(acc[rt][r]);
        }
        __syncthreads();
        const ushort8* sv = (const ushort8*)st;                 // 512 x 16B
        ushort8* hout = (ushort8*)(hb + (size_t)rowbase * FOUT);
        hout[threadIdx.x] = sv[threadIdx.x];
        hout[threadIdx.x + 256] = sv[threadIdx.x + 256];
    }
}

// ---------------------------------------------------------------------------
// Per-subgraph aggregate + norm + PReLU + pool + anchor (R13, unchanged).
// Thread t consumes chunk t's run for subgraph g (256 chunks, 256 threads).
// ---------------------------------------------------------------------------
__global__ __launch_bounds__(256) void agg_pool_kernel(const unsigned short* __restrict__ hb,
                                                       const unsigned short* __restrict__ bkt,
                                                       const unsigned* __restrict__ ofs,
                                                       const float* __restrict__ bias,
                                                       const float* __restrict__ prelu,
                                                       float* __restrict__ out) {
    __shared__ unsigned short hl[SSUB][FOUT];       // 16 KB bf16 bits
    __shared__ unsigned char  es[SSUB][64];         // 8 KB per-dst src lists
    __shared__ int   din[SSUB];
    __shared__ int   dout[SSUB];
    __shared__ float rout[SSUB];
    __shared__ float ps[4][FOUT];

    const int g = blockIdx.x;
    const int t = threadIdx.x;
    const int lane = t & 63;
    const int w = t >> 6;

    // load h tile (straight bf16 copy, 4 x ushort8 per thread)
    {
        const ushort8* hsrc = (const ushort8*)(hb + (size_t)g * SSUB * FOUT);
        ushort8* hdst = (ushort8*)&hl[0][0];
        for (int i = t; i < 1024; i += 256) hdst[i] = hsrc[i];
    }
    if (t < SSUB) { din[t] = 0; dout[t] = 0; }
    __syncthreads();

    // edge pass: thread t consumes chunk t's run for subgraph g
    {
        unsigned w32 = ofs[(size_t)t * BSUB + g];
        int st = (int)(w32 >> 16), cn = (int)(w32 & 0xffff);
        const unsigned short* ebb = bkt + ((size_t)t << 13) + st;
        for (int i = 0; i < cn; ++i) {
            unsigned e = ebb[i];
            int s = e >> 7, d = e & 127;
            int r = atomicAdd(&din[d], 1);
            es[d][r & 63] = (unsigned char)s;
            atomicAdd(&dout[s], 1);
        }
    }
    __syncthreads();
    if (t < SSUB) rout[t] = rsqrtf((float)max(dout[t], 1));
    __syncthreads();

    // register aggregation: wave w owns dst rows w, w+4, ...
    const float bv = bias[lane];
    const float a = prelu[0];
    float pool = 0.f;
#pragma unroll 4
    for (int ii = 0; ii < 32; ++ii) {
        int d = w + 4 * ii;
        int cd = min(din[d], 64);
        float accv = 0.f;
        const unsigned* ew = (const unsigned*)&es[d][0];
        int nw = (cd + 3) >> 2;
        for (int p = 0; p < nw; ++p) {
            unsigned wd = ew[p];                        // broadcast LDS read
            int rem = cd - p * 4;
#pragma unroll
            for (int b = 0; b < 4; ++b) {
                if (b < rem) {                          // wave-uniform predicate
                    int s = (wd >> (8 * b)) & 127;
                    accv += bf2f(hl[s][lane]) * rout[s];
                }
            }
        }
        float v = accv * rsqrtf((float)max(din[d], 1)) + bv;
        v = (v > 0.f) ? v : a * v;
        if (d == SSUB - 1)
            out[(size_t)(BSUB + g) * FOUT + lane] = v;  // anchor (wave 3)
        else
            pool += v;
    }
    ps[w][lane] = pool;
    __syncthreads();
    if (w == 0) {
        float s = (ps[0][lane] + ps[1][lane]) + (ps[2][lane] + ps[3][lane]);
        out[(size_t)g * FOUT + lane] = s * (1.0f / 127.0f);
    }
}

// ---------------------------------------------------------------------------
extern "C" void kernel_launch(void* const* d_in, const int* in_sizes, int n_in,
                              void* d_out, int out_size, void* d_ws, size_t ws_size,
                              hipStream_t stream) {
    const float* in_feat = (const float*)d_in[0];
    const float* W       = (const float*)d_in[1];
    const float* bias    = (const float*)d_in[2];
    const float* prelu   = (const float*)d_in[3];
    const int*   src     = (const int*)d_in[4];
    const int*   dst     = (const int*)d_in[5];
    float* out = (float*)d_out;

    char* ws = (char*)d_ws;
    short*          wfrag = (short*)(ws + 65536);                // 40 KB
    unsigned*       ofs   = (unsigned*)(ws + (2u << 20));        // 1 MB (256x1024 u32)
    unsigned short* bkt   = (unsigned short*)(ws + (4u << 20));  // 4 MB (256x8192 u16)
    unsigned short* hb    = (unsigned short*)(ws + (16u << 20)); // 16 MB bf16 h

    hipLaunchKernelGGL(bucket_prep_kernel, dim3(NCHUNK + 10), dim3(256), 0, stream,
                       src, dst, ofs, bkt, W, wfrag);
    hipLaunchKernelGGL(gemm_kernel,        dim3(NNODES/64),   dim3(256), 0, stream, in_feat, wfrag, hb);
    hipLaunchKernelGGL(agg_pool_kernel,    dim3(BSUB),        dim3(256), 0, stream, hb, bkt, ofs, bias, prelu, out);
}